// Round 2
// baseline (501.814 us; speedup 1.0000x reference)
//
#include <hip/hip_runtime.h>

// SectorAttentionV2 on MI355X (gfx950)  — round 2
// Layouts:
//   Qw[b][u][nh][cg8][p4][dc8][col64][d8]  bf16  (d8 contiguous 16B runs)
//   Kw/Vw[b][u][nh][cg8][ks4][dc8][col64][d8] bf16
//   biasw[b][nh][p][ks][w8192] f32

typedef unsigned short u16;
typedef unsigned int u32;
typedef __attribute__((ext_vector_type(8))) short bf16x8;
typedef __attribute__((ext_vector_type(4))) float f32x4;
typedef __attribute__((ext_vector_type(8))) unsigned short u16x8;
typedef __attribute__((ext_vector_type(4))) unsigned int u32x4;
typedef __attribute__((ext_vector_type(2))) unsigned int u32x2;

__device__ __forceinline__ u16 f2b(float f) {
  u32 u = __float_as_uint(f);
  return (u16)((u + 0x7FFFu + ((u >> 16) & 1u)) >> 16);  // RNE
}
__device__ __forceinline__ float b2f_lo(u32 d) { return __uint_as_float(d << 16); }
__device__ __forceinline__ float b2f_hi(u32 d) { return __uint_as_float(d & 0xffff0000u); }
__device__ __forceinline__ u32 cvt_pk(float lo, float hi) {
  u32 r;
  asm("v_cvt_pk_bf16_f32 %0, %1, %2" : "=v"(r) : "v"(lo), "v"(hi));
  return r;
}
#define GLDS(g, l)                                                              \
  __builtin_amdgcn_global_load_lds((const __attribute__((address_space(1))) void*)(g), \
                                   (__attribute__((address_space(3))) void*)(l), 16, 0, 0)

// ---------------- weight transpose + cvt ----------------
__global__ __launch_bounds__(256) void wt_kernel(const float* __restrict__ Wq,
                                                 const float* __restrict__ Wk,
                                                 const float* __restrict__ Wv,
                                                 u16* __restrict__ Wt) {
  const float* W = (blockIdx.y == 0) ? Wq : (blockIdx.y == 1) ? Wk : Wv;
  int g = blockIdx.x * 256 + threadIdx.x;
  int n = g >> 9, k = g & 511;
  Wt[(size_t)blockIdx.y * 262144 + g] = f2b(W[k * 512 + n]);
}

// ---------------- bias MLP ----------------
__global__ __launch_bounds__(256) void bias_kernel(
    const float* __restrict__ xpos, const float* __restrict__ spos,
    const float* __restrict__ pw1, const float* __restrict__ pb1,
    const float* __restrict__ bng, const float* __restrict__ bnb,
    const float* __restrict__ bnm, const float* __restrict__ bnv,
    const float* __restrict__ pw2, const float* __restrict__ pb2,
    float* __restrict__ biasw) {
  int t = threadIdx.x;
  int wl = t & 63, p = t >> 6;
  int n = blockIdx.x * 64 + wl;
  int b = n >> 13, w = n & 8191;

  float Am[16], Bm[16], Cm[16];
#pragma unroll
  for (int m = 0; m < 16; ++m) {
    float scv = bng[m] * rsqrtf(bnv[m] + 1e-5f);
    Am[m] = pw1[2 * m] * scv;
    Bm[m] = pw1[2 * m + 1] * scv;
    Cm[m] = (pb1[m] - bnm[m]) * scv + bnb[m];
  }
  size_t xi = ((size_t)(b * 32768 + p * 8192 + w)) * 2;
  float xp0 = xpos[xi], xp1 = xpos[xi + 1];
#pragma unroll
  for (int ks = 0; ks < 4; ++ks) {
    size_t si = ((size_t)((b * 4 + ks) * 8192 + w)) * 2;
    float r0 = xp0 - spos[si];
    float r1 = xp1 - spos[si + 1];
    float o[8];
#pragma unroll
    for (int oo = 0; oo < 8; ++oo) o[oo] = pb2[oo];
#pragma unroll
    for (int m = 0; m < 16; ++m) {
      float h = fmaxf(Am[m] * r0 + Bm[m] * r1 + Cm[m], 0.f);
#pragma unroll
      for (int oo = 0; oo < 8; ++oo) o[oo] += pw2[oo * 16 + m] * h;
    }
#pragma unroll
    for (int oo = 0; oo < 8; ++oo)
      biasw[((size_t)(((b * 8 + oo) * 4 + p) * 4 + ks)) * 8192 + w] = o[oo];
  }
}

// ---------------- Q GEMM: Q = x @ WqT + bq, 128x128 tile ----------------
__global__ __launch_bounds__(256, 3) void gemmq_kernel(const float* __restrict__ A,
                                                       const u16* __restrict__ Bt,
                                                       const float* __restrict__ biasv,
                                                       u16* __restrict__ Out) {
  __shared__ u16 lds[128 * 72 + 128 * 64];
  u16* Alds = lds;
  u16* Blds = lds + 128 * 72;
  const int t = threadIdx.x, lane = t & 63, wv = t >> 6;
  const int id = (int)blockIdx.x;
  const int lg = (id & 7) * 256 + (id >> 3);        // XCD bijective swizzle (2048 % 8 == 0)
  const int mtile = lg >> 2, ntile = lg & 3;        // n fastest -> A-panel L2 reuse per XCD
  const int mt = mtile * 128, nt = ntile * 128;
  const int fr = lane & 15, kg = lane >> 4;
  const int wm = (wv & 1) * 64, wn = (wv >> 1) * 64;

  f32x4 acc[4][4];
#pragma unroll
  for (int i = 0; i < 4; ++i)
#pragma unroll
    for (int j = 0; j < 4; ++j) acc[i][j] = (f32x4){0.f, 0.f, 0.f, 0.f};

  for (int kt = 0; kt < 512; kt += 64) {
    // stage A (f32 -> bf16 via v_cvt_pk_bf16_f32)
#pragma unroll
    for (int i = 0; i < 8; ++i) {
      int flat = i * 256 + t;
      int row = flat >> 4, c4 = (flat & 15) * 4;
      float4 v = *(const float4*)(A + (size_t)(mt + row) * 512 + kt + c4);
      u32x2 pk2;
      pk2.x = cvt_pk(v.x, v.y);
      pk2.y = cvt_pk(v.z, v.w);
      *(u32x2*)&Alds[row * 72 + c4] = pk2;
    }
    // stage B via global_load_lds, XOR-swizzled source (kseg ^ (row&7))
#pragma unroll
    for (int ii = 0; ii < 4; ++ii) {
      int inst = wv * 4 + ii;
      int row = inst * 8 + (lane >> 3);
      int kseg = (lane & 7) ^ (row & 7);
      const u16* src = Bt + (size_t)(nt + row) * 512 + kt + kseg * 8;
      GLDS(src, &Blds[inst * 512]);
    }
    __syncthreads();
#pragma unroll
    for (int kk = 0; kk < 64; kk += 32) {
      bf16x8 af[4], bf[4];
#pragma unroll
      for (int i = 0; i < 4; ++i)
        af[i] = *(const bf16x8*)&Alds[(wm + i * 16 + fr) * 72 + kk + kg * 8];
#pragma unroll
      for (int j = 0; j < 4; ++j) {
        int row = wn + j * 16 + fr;
        int kc = ((kk >> 3) + kg) ^ (row & 7);
        bf[j] = *(const bf16x8*)&Blds[row * 64 + kc * 8];
      }
#pragma unroll
      for (int i = 0; i < 4; ++i)
#pragma unroll
        for (int j = 0; j < 4; ++j)
          acc[i][j] = __builtin_amdgcn_mfma_f32_16x16x32_bf16(af[i], bf[j], acc[i][j], 0, 0, 0);
    }
    __syncthreads();
  }

  // epilogue: Clds transpose -> [cg][p][dc][col64][d8] coalesced 1KB stores
  u16* Clds = lds;  // 128*136 = 17408 u16 == Alds+Blds exactly
#pragma unroll
  for (int i = 0; i < 4; ++i)
#pragma unroll
    for (int r = 0; r < 4; ++r) {
      int row = wm + i * 16 + kg * 4 + r;
#pragma unroll
      for (int j = 0; j < 4; ++j) {
        int ch = wn + j * 16 + fr;
        Clds[row * 136 + ch] = f2b(acc[i][j][r] + biasv[nt + ch]);
      }
    }
  __syncthreads();
  const int b = mt >> 15, p = (mt >> 13) & 3, u = (mt >> 9) & 15, c0 = mt & 511;
  const int l8 = t & 63, w8 = t >> 6;
#pragma unroll
  for (int pp = 0; pp < 8; ++pp) {
    int item = w8 * 8 + pp;
    int cgi = item >> 4, nhs = (item >> 3) & 1, dc = item & 7;
    int nh = (nt >> 6) + nhs, cgg = (c0 >> 6) + cgi;
    size_t gaddr = ((((size_t)((b * 16 + u) * 8 + nh)) * 8 + cgg) * 16384) + p * 4096 + dc * 512 +
                   (size_t)l8 * 8;
    *(u16x8*)(Out + gaddr) = *(const u16x8*)&Clds[(cgi * 64 + l8) * 136 + nhs * 64 + dc * 8];
  }
}

// ---------------- fused K+V GEMM: BM=512, BN=32, BK=32, 512 threads ----------------
__global__ __launch_bounds__(512, 4) void gemmkv_kernel(const float* __restrict__ A,
                                                        const u16* __restrict__ BtK,
                                                        const u16* __restrict__ BtV,
                                                        const float* __restrict__ bK,
                                                        const float* __restrict__ bV,
                                                        u16* __restrict__ Kw,
                                                        u16* __restrict__ Vw) {
  __shared__ u16 lds[20480 + 2048];
  u16* Alds = lds;            // 512 rows x 32k, pad 40
  u16* BldsK = lds + 20480;   // 32 x 32
  u16* BldsV = lds + 21504;
  const int t = threadIdx.x, lane = t & 63, wv = t >> 6;
  const int id = (int)blockIdx.x;
  const int lg = (id & 7) * 256 + (id >> 3);
  const int mtile = lg >> 4, ntile = lg & 15;
  const int mt = mtile * 512, nt = ntile * 32;
  const int fr = lane & 15, kg = lane >> 4;
  const int wm = wv * 64;

  f32x4 accK[4][2], accV[4][2];
#pragma unroll
  for (int i = 0; i < 4; ++i)
#pragma unroll
    for (int j = 0; j < 2; ++j) {
      accK[i][j] = (f32x4){0.f, 0.f, 0.f, 0.f};
      accV[i][j] = (f32x4){0.f, 0.f, 0.f, 0.f};
    }

  for (int kt = 0; kt < 512; kt += 32) {
    // stage A: 512 rows x 32 k
#pragma unroll
    for (int pp = 0; pp < 2; ++pp) {
      int row = pp * 256 + (t >> 1);
      int kh = (t & 1) * 16;
      const float* ap = A + (size_t)(mt + row) * 512 + kt + kh;
#pragma unroll
      for (int c = 0; c < 4; ++c) {
        float4 v = *(const float4*)(ap + c * 4);
        u32x2 pk2;
        pk2.x = cvt_pk(v.x, v.y);
        pk2.y = cvt_pk(v.z, v.w);
        *(u32x2*)&Alds[row * 40 + kh + c * 4] = pk2;
      }
    }
    // stage B (K and V), swizzled source kseg ^ ((row>>1)&3)
    if (wv < 4) {
      int mat = wv >> 1, h = wv & 1;
      int row = h * 16 + (lane >> 2);
      int kseg = (lane & 3) ^ ((row >> 1) & 3);
      const u16* src = (mat ? BtV : BtK) + (size_t)(nt + row) * 512 + kt + kseg * 8;
      u16* dstbase = (mat ? BldsV : BldsK) + h * 512;
      GLDS(src, dstbase);
    }
    __syncthreads();
    bf16x8 af[4], bk8[2], bv8[2];
#pragma unroll
    for (int i = 0; i < 4; ++i)
      af[i] = *(const bf16x8*)&Alds[(wm + i * 16 + fr) * 40 + kg * 8];
#pragma unroll
    for (int j = 0; j < 2; ++j) {
      int row = j * 16 + fr;
      int ko = (kg ^ ((row >> 1) & 3)) * 8;
      bk8[j] = *(const bf16x8*)&BldsK[row * 32 + ko];
      bv8[j] = *(const bf16x8*)&BldsV[row * 32 + ko];
    }
#pragma unroll
    for (int i = 0; i < 4; ++i)
#pragma unroll
      for (int j = 0; j < 2; ++j) {
        accK[i][j] = __builtin_amdgcn_mfma_f32_16x16x32_bf16(af[i], bk8[j], accK[i][j], 0, 0, 0);
        accV[i][j] = __builtin_amdgcn_mfma_f32_16x16x32_bf16(af[i], bv8[j], accV[i][j], 0, 0, 0);
      }
    __syncthreads();
  }

  // epilogue: rows decompose as u=kg*4+r, ks=i, d3=wv, (nh,dt8,b from mtile)
  const int bb = mtile >> 6, nh = (mtile >> 3) & 7, dt8 = mtile & 7;
  const int cgg = nt >> 6, colb = nt & 63;
  u16* Clds = lds;  // 32 runs x 264
  auto epi = [&](const f32x4(&acc)[4][2], const float* __restrict__ biasv, u16* __restrict__ Outp) {
#pragma unroll
    for (int ksp = 0; ksp < 2; ++ksp) {
      __syncthreads();
#pragma unroll
      for (int ii = 0; ii < 2; ++ii)
#pragma unroll
        for (int j = 0; j < 2; ++j)
#pragma unroll
          for (int r = 0; r < 4; ++r) {
            int uu = kg * 4 + r, col = j * 16 + fr;
            Clds[(ii * 16 + uu) * 264 + col * 8 + wv] =
                f2b(acc[ksp * 2 + ii][j][r] + biasv[nt + col]);
          }
      __syncthreads();
      int run = t >> 4, l16 = t & 15;
      int uu = run & 15, ii = run >> 4;
      int ks = ksp * 2 + ii;
      size_t gb = ((((size_t)((bb * 16 + uu) * 8 + nh)) * 8 + cgg) * 4 + ks) * 4096 + dt8 * 512 +
                  colb * 8;
#pragma unroll
      for (int c = 0; c < 2; ++c) {
        int o = c * 128 + l16 * 8;
        *(u16x8*)(Outp + gb + o) = *(const u16x8*)&Clds[run * 264 + o];
      }
    }
  };
  epi(accK, bK, Kw);
  epi(accV, bV, Vw);
}

// ---------------- attention ----------------
// block = (b,u,cg64,nhPair); wave = (nh-of-pair, d-half); lane = col
__global__ __launch_bounds__(256, 4) void attn_kernel(const u16* __restrict__ Qw,
                                                      const u16* __restrict__ Kw,
                                                      const u16* __restrict__ Vw,
                                                      const float* __restrict__ biasw,
                                                      float* __restrict__ out) {
  __shared__ float lds[8256];  // exchange (4096) then out-stage [64col][129]
  const int t = threadIdx.x, lane = t & 63, wv = t >> 6;
  const int blk = blockIdx.x;
  const int nhp = blk & 3, cg = (blk >> 2) & 7, u = (blk >> 5) & 15, b = blk >> 9;
  const int nhl = wv >> 1, dh = wv & 1;
  const int nh = nhp * 2 + nhl;
  const size_t wbase = (((size_t)((b * 16 + u) * 8 + nh)) * 8 + cg) * 16384;
  const u16* qb = Qw + wbase;
  const u16* kb = Kw + wbase;
  const u16* vb = Vw + wbase;

  float sc[4][4];
#pragma unroll
  for (int p = 0; p < 4; ++p)
#pragma unroll
    for (int k = 0; k < 4; ++k) sc[p][k] = 0.f;

  // QK^T over this wave's d-half (4 chunks of 8)
#pragma unroll
  for (int c = 0; c < 4; ++c) {
    int off = (dh * 4 + c) * 512 + lane * 8;
    u32x4 qr[4], kr[4];
#pragma unroll
    for (int p = 0; p < 4; ++p) qr[p] = *(const u32x4*)(qb + p * 4096 + off);
#pragma unroll
    for (int k = 0; k < 4; ++k) kr[k] = *(const u32x4*)(kb + k * 4096 + off);
#pragma unroll
    for (int d4 = 0; d4 < 4; ++d4) {
      float qe[4], ke[4];
#pragma unroll
      for (int p = 0; p < 4; ++p) qe[p] = b2f_lo(qr[p][d4]);
#pragma unroll
      for (int k = 0; k < 4; ++k) ke[k] = b2f_lo(kr[k][d4]);
#pragma unroll
      for (int p = 0; p < 4; ++p)
#pragma unroll
        for (int k = 0; k < 4; ++k) sc[p][k] += qe[p] * ke[k];
#pragma unroll
      for (int p = 0; p < 4; ++p) qe[p] = b2f_hi(qr[p][d4]);
#pragma unroll
      for (int k = 0; k < 4; ++k) ke[k] = b2f_hi(kr[k][d4]);
#pragma unroll
      for (int p = 0; p < 4; ++p)
#pragma unroll
        for (int k = 0; k < 4; ++k) sc[p][k] += qe[p] * ke[k];
    }
  }

  // exchange partial d-half sums with partner wave (wv^1 flips dh, same nh)
#pragma unroll
  for (int pk = 0; pk < 16; ++pk) lds[(wv * 16 + pk) * 64 + lane] = sc[pk >> 2][pk & 3];
  __syncthreads();

  float a[4][4];
  const int w = u * 512 + cg * 64 + lane;
  const size_t bbase = ((size_t)(b * 8 + nh) * 16) * 8192 + w;
#pragma unroll
  for (int p = 0; p < 4; ++p) {
    float s0 = sc[p][0] + lds[((wv ^ 1) * 16 + p * 4 + 0) * 64 + lane];
    float s1 = sc[p][1] + lds[((wv ^ 1) * 16 + p * 4 + 1) * 64 + lane];
    float s2 = sc[p][2] + lds[((wv ^ 1) * 16 + p * 4 + 2) * 64 + lane];
    float s3 = sc[p][3] + lds[((wv ^ 1) * 16 + p * 4 + 3) * 64 + lane];
    s0 = s0 * 0.125f + biasw[bbase + (size_t)(p * 4 + 0) * 8192];
    s1 = s1 * 0.125f + biasw[bbase + (size_t)(p * 4 + 1) * 8192];
    s2 = s2 * 0.125f + biasw[bbase + (size_t)(p * 4 + 2) * 8192];
    s3 = s3 * 0.125f + biasw[bbase + (size_t)(p * 4 + 3) * 8192];
    float mx = fmaxf(fmaxf(s0, s1), fmaxf(s2, s3));
    float e0 = __expf(s0 - mx), e1 = __expf(s1 - mx), e2 = __expf(s2 - mx), e3 = __expf(s3 - mx);
    float inv = 1.f / (e0 + e1 + e2 + e3);
    a[p][0] = e0 * inv;
    a[p][1] = e1 * inv;
    a[p][2] = e2 * inv;
    a[p][3] = e3 * inv;
  }
  __syncthreads();  // lds: exchange -> out-stage reuse

  // PV: V held in regs (16 x 16B), out staged per p via LDS for coalesced flush
  u32x4 vr[4][4];
#pragma unroll
  for (int k = 0; k < 4; ++k)
#pragma unroll
    for (int c = 0; c < 4; ++c)
      vr[k][c] = *(const u32x4*)(vb + k * 4096 + (dh * 4 + c) * 512 + lane * 8);

  const int chb = nhl * 64 + dh * 32;
#pragma unroll
  for (int p = 0; p < 4; ++p) {
#pragma unroll
    for (int c = 0; c < 4; ++c) {
#pragma unroll
      for (int d4 = 0; d4 < 4; ++d4) {
        float lo = a[p][0] * b2f_lo(vr[0][c][d4]) + a[p][1] * b2f_lo(vr[1][c][d4]) +
                   a[p][2] * b2f_lo(vr[2][c][d4]) + a[p][3] * b2f_lo(vr[3][c][d4]);
        float hi = a[p][0] * b2f_hi(vr[0][c][d4]) + a[p][1] * b2f_hi(vr[1][c][d4]) +
                   a[p][2] * b2f_hi(vr[2][c][d4]) + a[p][3] * b2f_hi(vr[3][c][d4]);
        lds[lane * 129 + chb + c * 8 + d4 * 2 + 0] = lo;
        lds[lane * 129 + chb + c * 8 + d4 * 2 + 1] = hi;
      }
    }
    __syncthreads();
    // flush p: 128B-contiguous runs, 2 cols x 32ch per instruction
    size_t rbase = ((size_t)(b * 32768 + p * 8192 + u * 512 + cg * 64)) * 512 + nhp * 128;
    int chl = t & 31, colq = t >> 5;
#pragma unroll
    for (int cc = 0; cc < 4; ++cc)
#pragma unroll
      for (int cb = 0; cb < 8; ++cb) {
        int col = cb * 8 + colq;
        int ch = cc * 32 + chl;
        out[rbase + (size_t)col * 512 + ch] = lds[col * 129 + ch];
      }
    __syncthreads();
  }
}

// ---------------- launch ----------------
extern "C" void kernel_launch(void* const* d_in, const int* in_sizes, int n_in,
                              void* d_out, int out_size, void* d_ws, size_t ws_size,
                              hipStream_t stream) {
  (void)in_sizes; (void)n_in; (void)out_size; (void)ws_size;
  const float* s     = (const float*)d_in[0];
  const float* x     = (const float*)d_in[1];
  const float* s_pos = (const float*)d_in[2];
  const float* x_pos = (const float*)d_in[3];
  const float* Wq = (const float*)d_in[4];  const float* bq = (const float*)d_in[5];
  const float* Wk = (const float*)d_in[6];  const float* bk = (const float*)d_in[7];
  const float* Wv = (const float*)d_in[8];  const float* bv = (const float*)d_in[9];
  const float* pw1 = (const float*)d_in[10]; const float* pb1 = (const float*)d_in[11];
  const float* bng = (const float*)d_in[12]; const float* bnb = (const float*)d_in[13];
  const float* bnm = (const float*)d_in[14]; const float* bnv = (const float*)d_in[15];
  const float* pw2 = (const float*)d_in[16]; const float* pb2 = (const float*)d_in[17];
  float* out = (float*)d_out;

  char* ws = (char*)d_ws;
  u16* Qw = (u16*)ws;                           // 67,108,864 B
  u16* Kw = (u16*)(ws + 67108864);              // 67,108,864 B
  u16* Vw = (u16*)(ws + 134217728);             // 67,108,864 B
  float* biasw = (float*)(ws + 201326592);      //  8,388,608 B
  u16* Wt = (u16*)(ws + 209715200);             //  1,572,864 B

  wt_kernel<<<dim3(1024, 3), 256, 0, stream>>>(Wq, Wk, Wv, Wt);
  bias_kernel<<<dim3(256), 256, 0, stream>>>(x_pos, s_pos, pw1, pb1, bng, bnb, bnm, bnv,
                                             pw2, pb2, biasw);
  gemmq_kernel<<<dim3(2048), 256, 0, stream>>>(x, Wt, bq, Qw);
  gemmkv_kernel<<<dim3(2048), 512, 0, stream>>>(s, Wt + 262144, Wt + 524288, bk, bv, Kw, Vw);
  attn_kernel<<<dim3(1024), 256, 0, stream>>>(Qw, Kw, Vw, biasw, out);
}

// Round 3
// 397.456 us; speedup vs baseline: 1.2626x; 1.2626x over previous
//
#include <hip/hip_runtime.h>

// SectorAttentionV2 on MI355X (gfx950) — round 3
//   All Q/K/V as PLAIN row-major bf16 [65536][512]; attention does the
//   window gather directly (all reads coalesced or full-line).

typedef unsigned short u16;
typedef unsigned int u32;
typedef __attribute__((ext_vector_type(8))) short bf16x8;
typedef __attribute__((ext_vector_type(4))) float f32x4;
typedef __attribute__((ext_vector_type(8))) unsigned short u16x8;
typedef __attribute__((ext_vector_type(4))) unsigned int u32x4;
typedef __attribute__((ext_vector_type(2))) unsigned int u32x2;

__device__ __forceinline__ u16 f2b(float f) {
  u32 u = __float_as_uint(f);
  return (u16)((u + 0x7FFFu + ((u >> 16) & 1u)) >> 16);  // RNE
}
__device__ __forceinline__ float b2f(u16 v) { return __uint_as_float(((u32)v) << 16); }
__device__ __forceinline__ float b2f_lo(u32 d) { return __uint_as_float(d << 16); }
__device__ __forceinline__ float b2f_hi(u32 d) { return __uint_as_float(d & 0xffff0000u); }
__device__ __forceinline__ u32 cvt_pk(float lo, float hi) {
  u32 r;
  asm("v_cvt_pk_bf16_f32 %0, %1, %2" : "=v"(r) : "v"(lo), "v"(hi));
  return r;
}
#define GLDS(g, l)                                                                     \
  __builtin_amdgcn_global_load_lds((const __attribute__((address_space(1))) void*)(g), \
                                   (__attribute__((address_space(3))) void*)(l), 16, 0, 0)

// ---------------- weight transpose + cvt ----------------
__global__ __launch_bounds__(256) void wt_kernel(const float* __restrict__ Wq,
                                                 const float* __restrict__ Wk,
                                                 const float* __restrict__ Wv,
                                                 u16* __restrict__ Wt) {
  const float* W = (blockIdx.y == 0) ? Wq : (blockIdx.y == 1) ? Wk : Wv;
  int g = blockIdx.x * 256 + threadIdx.x;
  int n = g >> 9, k = g & 511;
  Wt[(size_t)blockIdx.y * 262144 + g] = f2b(W[k * 512 + n]);
}

// ---------------- bias MLP ----------------
// biasw[((b*8+nh)*4+p)*4+ks][w8192] f32
__global__ __launch_bounds__(256) void bias_kernel(
    const float* __restrict__ xpos, const float* __restrict__ spos,
    const float* __restrict__ pw1, const float* __restrict__ pb1,
    const float* __restrict__ bng, const float* __restrict__ bnb,
    const float* __restrict__ bnm, const float* __restrict__ bnv,
    const float* __restrict__ pw2, const float* __restrict__ pb2,
    float* __restrict__ biasw) {
  int t = threadIdx.x;
  int wl = t & 63, p = t >> 6;
  int n = blockIdx.x * 64 + wl;
  int b = n >> 13, w = n & 8191;

  float Am[16], Bm[16], Cm[16];
#pragma unroll
  for (int m = 0; m < 16; ++m) {
    float scv = bng[m] * rsqrtf(bnv[m] + 1e-5f);
    Am[m] = pw1[2 * m] * scv;
    Bm[m] = pw1[2 * m + 1] * scv;
    Cm[m] = (pb1[m] - bnm[m]) * scv + bnb[m];
  }
  size_t xi = ((size_t)(b * 32768 + p * 8192 + w)) * 2;
  float xp0 = xpos[xi], xp1 = xpos[xi + 1];
#pragma unroll
  for (int ks = 0; ks < 4; ++ks) {
    size_t si = ((size_t)((b * 4 + ks) * 8192 + w)) * 2;
    float r0 = xp0 - spos[si];
    float r1 = xp1 - spos[si + 1];
    float o[8];
#pragma unroll
    for (int oo = 0; oo < 8; ++oo) o[oo] = pb2[oo];
#pragma unroll
    for (int m = 0; m < 16; ++m) {
      float h = fmaxf(Am[m] * r0 + Bm[m] * r1 + Cm[m], 0.f);
#pragma unroll
      for (int oo = 0; oo < 8; ++oo) o[oo] += pw2[oo * 16 + m] * h;
    }
#pragma unroll
    for (int oo = 0; oo < 8; ++oo)
      biasw[((size_t)(((b * 8 + oo) * 4 + p) * 4 + ks)) * 8192 + w] = o[oo];
  }
}

// ---------------- GEMM: Out[m][c] = A(f32)[65536x512] @ Bt(bf16 [n][k]) + bias, row-major bf16 ----------------
__global__ __launch_bounds__(256, 3) void gemm_kernel(const float* __restrict__ A,
                                                      const u16* __restrict__ Bt,
                                                      const float* __restrict__ biasv,
                                                      u16* __restrict__ Out) {
  __shared__ u16 lds[128 * 72 + 128 * 64];
  u16* Alds = lds;
  u16* Blds = lds + 128 * 72;
  const int t = threadIdx.x, lane = t & 63, wv = t >> 6;
  const int id = (int)blockIdx.x;
  const int lg = (id & 7) * 256 + (id >> 3);  // XCD bijective swizzle (2048 % 8 == 0)
  const int mt = (lg >> 2) * 128, nt = (lg & 3) * 128;  // n fastest: A-panel L2 reuse
  const int fr = lane & 15, kg = lane >> 4;
  const int wm = (wv & 1) * 64, wn = (wv >> 1) * 64;

  f32x4 acc[4][4];
#pragma unroll
  for (int i = 0; i < 4; ++i)
#pragma unroll
    for (int j = 0; j < 4; ++j) acc[i][j] = (f32x4){0.f, 0.f, 0.f, 0.f};

  for (int kt = 0; kt < 512; kt += 64) {
#pragma unroll
    for (int i = 0; i < 8; ++i) {
      int flat = i * 256 + t;
      int row = flat >> 4, c4 = (flat & 15) * 4;
      float4 v = *(const float4*)(A + (size_t)(mt + row) * 512 + kt + c4);
      u32x2 pk2;
      pk2.x = cvt_pk(v.x, v.y);
      pk2.y = cvt_pk(v.z, v.w);
      *(u32x2*)&Alds[row * 72 + c4] = pk2;
    }
#pragma unroll
    for (int ii = 0; ii < 4; ++ii) {
      int inst = wv * 4 + ii;
      int row = inst * 8 + (lane >> 3);
      int kseg = (lane & 7) ^ (row & 7);
      const u16* src = Bt + (size_t)(nt + row) * 512 + kt + kseg * 8;
      GLDS(src, &Blds[inst * 512]);
    }
    __syncthreads();
#pragma unroll
    for (int kk = 0; kk < 64; kk += 32) {
      bf16x8 af[4], bfr[4];
#pragma unroll
      for (int i = 0; i < 4; ++i)
        af[i] = *(const bf16x8*)&Alds[(wm + i * 16 + fr) * 72 + kk + kg * 8];
#pragma unroll
      for (int j = 0; j < 4; ++j) {
        int row = wn + j * 16 + fr;
        int kc = ((kk >> 3) + kg) ^ (row & 7);
        bfr[j] = *(const bf16x8*)&Blds[row * 64 + kc * 8];
      }
#pragma unroll
      for (int i = 0; i < 4; ++i)
#pragma unroll
        for (int j = 0; j < 4; ++j)
          acc[i][j] = __builtin_amdgcn_mfma_f32_16x16x32_bf16(af[i], bfr[j], acc[i][j], 0, 0, 0);
    }
    __syncthreads();
  }

  // epilogue: stage to LDS (pad 136), flush row-major coalesced (1KB/instr)
  u16* Clds = lds;  // 128*136 = 17408 u16 == exactly the LDS array
#pragma unroll
  for (int i = 0; i < 4; ++i)
#pragma unroll
    for (int r = 0; r < 4; ++r) {
      int row = wm + i * 16 + kg * 4 + r;
#pragma unroll
      for (int j = 0; j < 4; ++j) {
        int ch = wn + j * 16 + fr;
        Clds[row * 136 + ch] = f2b(acc[i][j][r] + biasv[nt + ch]);
      }
    }
  __syncthreads();
#pragma unroll
  for (int c = 0; c < 8; ++c) {
    int off = c * 2048 + t * 8;
    int row = off >> 7, col = off & 127;
    *(u16x8*)(Out + (size_t)(mt + row) * 512 + nt + col) = *(const u16x8*)&Clds[row * 136 + col];
  }
}

// ---------------- attention ----------------
// block = (b,u,cg8,nh8); lane = col within cg; wave w owns d in [16w,16w+16)
__global__ __launch_bounds__(256, 4) void attn_kernel(const u16* __restrict__ Qt,
                                                      const u16* __restrict__ Kt,
                                                      const u16* __restrict__ Vt,
                                                      const float* __restrict__ biasw,
                                                      float* __restrict__ out) {
  __shared__ float slds[4 * 16 * 64];  // 16 KB partial-score exchange
  const int t = threadIdx.x, lane = t & 63, wv = t >> 6;
  const int blk = blockIdx.x;
  const int nh = blk & 7, cg = (blk >> 3) & 7, u = (blk >> 6) & 15, b = blk >> 10;
  const int col = cg * 64 + lane;
  const int chb = nh * 64 + wv * 16;

  // Q: per-lane-row 2x16B loads per p
  u32x4 q0[4], q1[4];
#pragma unroll
  for (int p = 0; p < 4; ++p) {
    const u16* qp = Qt + (size_t)(b * 32768 + p * 8192 + u * 512 + col) * 512 + chb;
    q0[p] = *(const u32x4*)qp;
    q1[p] = *(const u32x4*)(qp + 8);
  }

  // K rows: m = b*32768 + nh*4096 + d*64 + ks*16 + u ; col c = cg*64+lane
  const size_t kvrow = (size_t)(b * 32768 + nh * 4096 + wv * 16 * 64 + u);
  const u16* kbase = Kt + kvrow * 512 + col;

  float sc[4][4];
#pragma unroll
  for (int p = 0; p < 4; ++p)
#pragma unroll
    for (int k = 0; k < 4; ++k) sc[p][k] = 0.f;

#pragma unroll
  for (int dd = 0; dd < 16; ++dd) {
    float kv[4];
#pragma unroll
    for (int ks = 0; ks < 4; ++ks) kv[ks] = b2f(kbase[(size_t)(dd * 64 + ks * 16) * 512]);
    float qd[4];
#pragma unroll
    for (int p = 0; p < 4; ++p) {
      u32 word = (dd < 8) ? q0[p][(dd >> 1) & 3] : q1[p][(dd >> 1) & 3];
      qd[p] = (dd & 1) ? b2f_hi(word) : b2f_lo(word);
    }
#pragma unroll
    for (int p = 0; p < 4; ++p)
#pragma unroll
      for (int ks = 0; ks < 4; ++ks) sc[p][ks] += qd[p] * kv[ks];
  }

  // exchange: sum partial d-slices across the 4 waves
#pragma unroll
  for (int pk = 0; pk < 16; ++pk) slds[(wv * 16 + pk) * 64 + lane] = sc[pk >> 2][pk & 3];
  __syncthreads();

  float a[4][4];
  const size_t bbase = ((size_t)(b * 8 + nh) * 16) * 8192 + u * 512 + col;
#pragma unroll
  for (int p = 0; p < 4; ++p) {
    float s[4];
#pragma unroll
    for (int ks = 0; ks < 4; ++ks) {
      int pk = p * 4 + ks;
      float tot = slds[(0 * 16 + pk) * 64 + lane] + slds[(1 * 16 + pk) * 64 + lane] +
                  slds[(2 * 16 + pk) * 64 + lane] + slds[(3 * 16 + pk) * 64 + lane];
      s[ks] = tot * 0.125f + biasw[bbase + (size_t)pk * 8192];
    }
    float mx = fmaxf(fmaxf(s[0], s[1]), fmaxf(s[2], s[3]));
    float e0 = __expf(s[0] - mx), e1 = __expf(s[1] - mx), e2 = __expf(s[2] - mx),
          e3 = __expf(s[3] - mx);
    float inv = 1.f / (e0 + e1 + e2 + e3);
    a[p][0] = e0 * inv; a[p][1] = e1 * inv; a[p][2] = e2 * inv; a[p][3] = e3 * inv;
  }

  // PV over this wave's 16 d's; output = full 64B line per (p,lane)
  const u16* vbase = Vt + kvrow * 512 + col;
  float o[4][16];
#pragma unroll
  for (int p = 0; p < 4; ++p)
#pragma unroll
    for (int dd = 0; dd < 16; ++dd) o[p][dd] = 0.f;
#pragma unroll
  for (int dd = 0; dd < 16; ++dd) {
    float vvv[4];
#pragma unroll
    for (int ks = 0; ks < 4; ++ks) vvv[ks] = b2f(vbase[(size_t)(dd * 64 + ks * 16) * 512]);
#pragma unroll
    for (int p = 0; p < 4; ++p)
      o[p][dd] = a[p][0] * vvv[0] + a[p][1] * vvv[1] + a[p][2] * vvv[2] + a[p][3] * vvv[3];
  }
#pragma unroll
  for (int p = 0; p < 4; ++p) {
    float* op = out + (size_t)(b * 32768 + p * 8192 + u * 512 + col) * 512 + chb;
#pragma unroll
    for (int c4 = 0; c4 < 4; ++c4) {
      float4 vv = {o[p][c4 * 4 + 0], o[p][c4 * 4 + 1], o[p][c4 * 4 + 2], o[p][c4 * 4 + 3]};
      *(float4*)(op + c4 * 4) = vv;
    }
  }
}

// ---------------- launch ----------------
extern "C" void kernel_launch(void* const* d_in, const int* in_sizes, int n_in,
                              void* d_out, int out_size, void* d_ws, size_t ws_size,
                              hipStream_t stream) {
  (void)in_sizes; (void)n_in; (void)out_size; (void)ws_size;
  const float* s     = (const float*)d_in[0];
  const float* x     = (const float*)d_in[1];
  const float* s_pos = (const float*)d_in[2];
  const float* x_pos = (const float*)d_in[3];
  const float* Wq = (const float*)d_in[4];  const float* bq = (const float*)d_in[5];
  const float* Wk = (const float*)d_in[6];  const float* bk = (const float*)d_in[7];
  const float* Wv = (const float*)d_in[8];  const float* bv = (const float*)d_in[9];
  const float* pw1 = (const float*)d_in[10]; const float* pb1 = (const float*)d_in[11];
  const float* bng = (const float*)d_in[12]; const float* bnb = (const float*)d_in[13];
  const float* bnm = (const float*)d_in[14]; const float* bnv = (const float*)d_in[15];
  const float* pw2 = (const float*)d_in[16]; const float* pb2 = (const float*)d_in[17];
  float* out = (float*)d_out;

  char* ws = (char*)d_ws;
  u16* Qt = (u16*)ws;                        // 67,108,864 B
  u16* Kt = (u16*)(ws + 67108864);           // 67,108,864 B
  u16* Vt = (u16*)(ws + 134217728);          // 67,108,864 B
  float* biasw = (float*)(ws + 201326592);   //  8,388,608 B
  u16* Wt = (u16*)(ws + 209715200);          //  1,572,864 B

  wt_kernel<<<dim3(1024, 3), 256, 0, stream>>>(Wq, Wk, Wv, Wt);
  bias_kernel<<<dim3(256), 256, 0, stream>>>(x_pos, s_pos, pw1, pb1, bng, bnb, bnm, bnv,
                                             pw2, pb2, biasw);
  gemm_kernel<<<dim3(2048), 256, 0, stream>>>(x, Wt, bq, Qt);
  gemm_kernel<<<dim3(2048), 256, 0, stream>>>(s, Wt + 262144, bk, Kt);
  gemm_kernel<<<dim3(2048), 256, 0, stream>>>(s, Wt + 524288, bv, Vt);
  attn_kernel<<<dim3(2048), 256, 0, stream>>>(Qt, Kt, Vt, biasw, out);
}